// Round 3
// baseline (251.934 us; speedup 1.0000x reference)
//
#include <hip/hip_runtime.h>

// Problem: B=64, L=512, D=768, S=8, HOP=3, LAMB=0.5
// Output depends only on sentence segments s in {5,6,7}:
//   g-path needs sent7; conv path c2[:,:,7] needs c1[6],c1[7] -> sent5..7.
// Float dtype (fp32 vs bf16) is DETECTED at runtime from bert's bit patterns;
// seg_bounds int32 vs int64 detected from sb32[1]==0.
// Workspace (fp32): sentF 64x2304 | accs g1(64x768) c1(64x1536) g2(64x768)
// c2(64x768) | flag(1)  => ~1.54 MB.

typedef unsigned short u16;
typedef short short8 __attribute__((ext_vector_type(8)));
typedef float f32x4 __attribute__((ext_vector_type(4)));

__device__ __forceinline__ float bf2f(u16 h) {
    unsigned int u = ((unsigned int)h) << 16;
    float f;
    __builtin_memcpy(&f, &u, 4);
    return f;
}
__device__ __forceinline__ u16 f2bf(float f) {
    unsigned int u;
    __builtin_memcpy(&u, &f, 4);
    u = (u + 0x7fffu + ((u >> 16) & 1u)) >> 16;  // RNE
    return (u16)u;
}
__device__ __forceinline__ float sigm(float x) { return 1.0f / (1.0f + __expf(-x)); }

// generic scalar load: bf16 bits or fp32
__device__ __forceinline__ float ldv(const void* p, long i, bool bf) {
    return bf ? bf2f(((const u16*)p)[i]) : ((const float*)p)[i];
}

// dtype detector: even-indexed u16s of fp32 N(0,1) data are mantissa bits
// (uniform -> ~6% in-window); of bf16 data they are bf16 values (~99%).
__device__ __forceinline__ bool detect_bf16(const u16* bert) {
    int hits = 0;
#pragma unroll
    for (int i = 0; i < 256; i += 2) {
        const int e = (bert[i] >> 7) & 0xFF;
        hits += (e >= 115 && e <= 130) ? 1 : 0;
    }
    return hits > 64;
}

// ---------------------------------------------------------------------------
// k1: zero accumulators + segment mean pool (s = 5,6,7) into fp32 sentF
// ---------------------------------------------------------------------------
__global__ __launch_bounds__(256) void k1_pool(
    const void* __restrict__ bertv, const int* __restrict__ sb,
    float* __restrict__ sentF, float* __restrict__ accs, float* __restrict__ flagp)
{
    const int u = blockIdx.x, t = threadIdx.x;
#pragma unroll
    for (int i = 0; i < 5; ++i) accs[u * 1280 + i * 256 + t] = 0.0f;  // 192*1280
    const bool bf = detect_bf16((const u16*)bertv);
    const bool is64 = (sb[1] == 0);  // int64 low/high word interleave
    if (t == 0) flagp[0] = bf ? 1.0f : 0.0f;
    const int b = u / 3, si = u % 3, s = 5 + si;
    const int i0 = b * 9 + s, i1 = i0 + 1;
    int st = is64 ? sb[2 * i0] : sb[i0];
    int en = is64 ? sb[2 * i1] : sb[i1];
    st = st < 0 ? 0 : (st > 511 ? 511 : st);
    en = en <= st ? st + 1 : (en > 512 ? 512 : en);
    float a0 = 0.0f, a1 = 0.0f, a2 = 0.0f;
    if (bf) {
        const u16* base = (const u16*)bertv + (size_t)b * 512 * 768;
        for (int l = st; l < en; ++l) {
            const u16* rp = base + l * 768;
            a0 += bf2f(rp[t]);
            a1 += bf2f(rp[t + 256]);
            a2 += bf2f(rp[t + 512]);
        }
    } else {
        const float* base = (const float*)bertv + (size_t)b * 512 * 768;
        for (int l = st; l < en; ++l) {
            const float* rp = base + l * 768;
            a0 += rp[t];
            a1 += rp[t + 256];
            a2 += rp[t + 512];
        }
    }
    const float inv = 1.0f / (float)(en - st);
    float* o = sentF + b * 2304 + si * 768;
    o[t] = a0 * inv;
    o[t + 256] = a1 * inv;
    o[t + 512] = a2 * inv;
}

// ---------------------------------------------------------------------------
// GEMM core: out(64 x Nout) += x(64 x K) @ B^T, 64x64 tile, K-chunk [k0,k0+256).
// x is always fp32 (workspace). Weights dtype via `bf`.
// XMODE 0: x raw. XMODE 1: x = tanh(raw + bias[k % 768]).
// WMODE 0: W is [k][n] row-major, n-dim 768 (gc1_w/gc2_w).
// WMODE 1: conv weights (O=768, I=768, 3): B[n][k=kb*768+i] = W[n*2304+i*3+kb].
// mfma_f32_16x16x32_bf16; A[m=lane&15][k=quad*8+j]; B same; C/D col=lane&15,
// row=quad*4+reg.
// ---------------------------------------------------------------------------
template <int XMODE, int WMODE>
__device__ __forceinline__ void gemm_core(
    const float* __restrict__ x, int xstride, const void* __restrict__ bias,
    const void* __restrict__ W, bool bf,
    float* __restrict__ out, int ostride,
    int n0, int k0, u16* As, u16* Bs)
{
    const int t = threadIdx.x;
    const int r = t >> 2;             // 0..63
    const int cseg = (t & 3) * 32;    // 0,32,64,96
    const int wave = t >> 6, lane = t & 63;
    const int lm = lane & 15, lq = lane >> 4;
    f32x4 acc[4] = {};

    for (int kk = 0; kk < 256; kk += 128) {
        const int kg = k0 + kk;
        // ---- stage x -> As (fp32 -> bf16), row stride 136 ----
        {
            const float* xp = x + (size_t)r * xstride + (kg + cseg);
            u16* dst = As + r * 136 + cseg;
#pragma unroll
            for (int i = 0; i < 8; ++i) {
                float4 v = ((const float4*)xp)[i];
                if (XMODE == 1) {
                    int kb = kg + cseg + i * 4;
                    if (kb >= 768) kb -= 768;   // K <= 1536, 4-aligned
                    v.x = tanhf(v.x + ldv(bias, kb, bf));
                    v.y = tanhf(v.y + ldv(bias, kb + 1, bf));
                    v.z = tanhf(v.z + ldv(bias, kb + 2, bf));
                    v.w = tanhf(v.w + ldv(bias, kb + 3, bf));
                }
                ((ushort4*)dst)[i] = make_ushort4(f2bf(v.x), f2bf(v.y), f2bf(v.z), f2bf(v.w));
            }
        }
        // ---- stage W -> Bs as [n][k], row stride 136 ----
        if (WMODE == 0) {
            const int p = t >> 2;             // k-pair: k = 2p, 2p+1
            const int nseg = (t & 3) * 16;    // 16 n's
            u16 q0[16], q1[16];
            if (bf) {
                const u16* w0 = (const u16*)W + (size_t)(kg + 2 * p) * 768 + n0 + nseg;
                ((uint4*)q0)[0] = ((const uint4*)w0)[0];
                ((uint4*)q0)[1] = ((const uint4*)w0)[1];
                ((uint4*)q1)[0] = ((const uint4*)(w0 + 768))[0];
                ((uint4*)q1)[1] = ((const uint4*)(w0 + 768))[1];
            } else {
                const float* w0 = (const float*)W + (size_t)(kg + 2 * p) * 768 + n0 + nseg;
#pragma unroll
                for (int e = 0; e < 4; ++e) {
                    float4 v0 = ((const float4*)w0)[e];
                    float4 v1 = ((const float4*)(w0 + 768))[e];
                    q0[4 * e] = f2bf(v0.x); q0[4 * e + 1] = f2bf(v0.y);
                    q0[4 * e + 2] = f2bf(v0.z); q0[4 * e + 3] = f2bf(v0.w);
                    q1[4 * e] = f2bf(v1.x); q1[4 * e + 1] = f2bf(v1.y);
                    q1[4 * e + 2] = f2bf(v1.z); q1[4 * e + 3] = f2bf(v1.w);
                }
            }
#pragma unroll
            for (int e = 0; e < 16; ++e)
                *(ushort2*)(Bs + (nseg + e) * 136 + 2 * p) = make_ushort2(q0[e], q1[e]);
        } else {
            // conv: within a 128-chunk, kb = kg/768 is constant (768 = 6*128)
            const int kb = kg / 768;
            const int i0 = kg - kb * 768;
            u16 tmp[32];
            if (bf) {
                const u16* wp = (const u16*)W + (size_t)(n0 + r) * 2304 + (size_t)(i0 + cseg) * 3 + kb;
#pragma unroll
                for (int j = 0; j < 32; ++j) tmp[j] = wp[j * 3];
            } else {
                const float* wp = (const float*)W + (size_t)(n0 + r) * 2304 + (size_t)(i0 + cseg) * 3 + kb;
#pragma unroll
                for (int j = 0; j < 32; ++j) tmp[j] = f2bf(wp[j * 3]);
            }
            u16* dst = Bs + r * 136 + cseg;
#pragma unroll
            for (int q = 0; q < 8; ++q)
                ((ushort4*)dst)[q] = ((ushort4*)tmp)[q];
        }
        __syncthreads();
        const u16* ap = As + (wave * 16 + lm) * 136 + lq * 8;
        const u16* bp = Bs + lm * 136 + lq * 8;
#pragma unroll
        for (int ks = 0; ks < 4; ++ks) {
            short8 af = *(const short8*)(ap + ks * 32);
#pragma unroll
            for (int nf = 0; nf < 4; ++nf) {
                short8 bfr = *(const short8*)(bp + nf * 16 * 136 + ks * 32);
                acc[nf] = __builtin_amdgcn_mfma_f32_16x16x32_bf16(af, bfr, acc[nf], 0, 0, 0);
            }
        }
        __syncthreads();
    }
#pragma unroll
    for (int nf = 0; nf < 4; ++nf) {
#pragma unroll
        for (int rg = 0; rg < 4; ++rg) {
            const int row = wave * 16 + lq * 4 + rg;
            const int col = n0 + nf * 16 + lm;
            atomicAdd(out + (size_t)row * ostride + col, acc[nf][rg]);
        }
    }
}

// Stage A: g1pre = sent7 @ gc1_w (K=768); c1_6 (K=2304, x=[s5|s6|s7]); c1_7 (K=1536, x=[s6|s7])
__global__ __launch_bounds__(256) void k2_gemm_a(
    const float* __restrict__ sentF, const void* __restrict__ gc1w,
    const void* __restrict__ c1w, float* __restrict__ g1acc, float* __restrict__ c1acc,
    const float* __restrict__ flagp)
{
    __shared__ u16 As[64 * 136];
    __shared__ u16 Bs[64 * 136];
    const bool bf = flagp[0] > 0.5f;
    const int u = blockIdx.x;
    if (u < 36) {
        gemm_core<0, 0>(sentF + 1536, 2304, nullptr, gc1w, bf, g1acc, 768,
                        (u / 3) * 64, (u % 3) * 256, As, Bs);
    } else if (u < 144) {
        const int v = u - 36;
        gemm_core<0, 1>(sentF, 2304, nullptr, c1w, bf, c1acc, 1536,
                        (v / 9) * 64, (v % 9) * 256, As, Bs);
    } else {
        const int v = u - 144;
        gemm_core<0, 1>(sentF + 768, 2304, nullptr, c1w, bf, c1acc + 768, 1536,
                        (v / 6) * 64, (v % 6) * 256, As, Bs);
    }
}

// Stage B: g2pre = tanh(g1+gc1_b) @ gc2_w (K=768); c2pre = tanh(c1+c1b) @ W2 (K=1536)
__global__ __launch_bounds__(256) void k3_gemm_b(
    const float* __restrict__ g1acc, const float* __restrict__ c1acc,
    const void* __restrict__ gc2w, const void* __restrict__ c2w,
    const void* __restrict__ gc1b, const void* __restrict__ c1b,
    float* __restrict__ g2acc, float* __restrict__ c2acc,
    const float* __restrict__ flagp)
{
    __shared__ u16 As[64 * 136];
    __shared__ u16 Bs[64 * 136];
    const bool bf = flagp[0] > 0.5f;
    const int u = blockIdx.x;
    if (u < 36) {
        gemm_core<1, 0>(g1acc, 768, gc1b, gc2w, bf, g2acc, 768,
                        (u / 3) * 64, (u % 3) * 256, As, Bs);
    } else {
        const int v = u - 36;
        gemm_core<1, 1>(c1acc, 1536, c1b, c2w, bf, c2acc, 768,
                        (v / 6) * 64, (v % 6) * 256, As, Bs);
    }
}

// ---------------------------------------------------------------------------
// k4: per-batch refine chains + softmax + fc2
// ---------------------------------------------------------------------------
__device__ __forceinline__ float block_sum(float v, float* red) {
#pragma unroll
    for (int m = 1; m < 64; m <<= 1) v += __shfl_xor(v, m, 64);
    const int wave = threadIdx.x >> 6, lane = threadIdx.x & 63;
    if (lane == 0) red[wave] = v;
    __syncthreads();
    const float r = red[0] + red[1] + red[2] + red[3];
    __syncthreads();
    return r;
}

__global__ __launch_bounds__(256) void k4_final(
    const float* __restrict__ sentF, const float* __restrict__ g2acc,
    const float* __restrict__ c2acc,
    const void* __restrict__ gc2b, const void* __restrict__ c2b,
    const void* __restrict__ lng, const void* __restrict__ lnb,
    const void* __restrict__ target, const void* __restrict__ fc2w,
    const void* __restrict__ fc2b, void* __restrict__ outp,
    const float* __restrict__ flagp)
{
    __shared__ float red[4];
    const bool bf = flagp[0] > 0.5f;
    const int t = threadIdx.x, b = blockIdx.x;
    float s_[3], g_[3], bb_[3];
    const float* srow = sentF + b * 2304 + 1536;  // sent7
#pragma unroll
    for (int i = 0; i < 3; ++i) {
        const int d = t + 256 * i;
        s_[i] = srow[d];
        g_[i] = ldv(lng, d, bf);
        bb_[i] = ldv(lnb, d, bf);
    }

    auto refine2 = [&](float* yv) {
#pragma unroll
        for (int it = 0; it < 2; ++it) {
            const float c = block_sum(yv[0] * s_[0] + yv[1] * s_[1] + yv[2] * s_[2], red);
            float tt[3], sm = 0.0f, sq = 0.0f;
#pragma unroll
            for (int i = 0; i < 3; ++i) {
                tt[i] = sigm(c * s_[i]);
                sm += tt[i];
                sq += tt[i] * tt[i];
            }
            const float m = block_sum(sm, red) * (1.0f / 768.0f);
            const float q = block_sum(sq, red) * (1.0f / 768.0f);
            const float inv = rsqrtf(fmaxf(q - m * m, 0.0f) + 1e-5f);
#pragma unroll
            for (int i = 0; i < 3; ++i)
                yv[i] = 0.5f * ((tt[i] - m) * inv * g_[i] + bb_[i]) + s_[i];
        }
    };

    float a3[3], a4[3], a5[3], y[3];
#pragma unroll
    for (int i = 0; i < 3; ++i) {
        const int d = t + 256 * i;
        y[i] = tanhf(g2acc[b * 768 + d] + ldv(gc2b, d, bf));
    }
    refine2(y);
    a3[0] = y[0]; a3[1] = y[1]; a3[2] = y[2];
#pragma unroll
    for (int i = 0; i < 3; ++i) {
        const int d = t + 256 * i;
        y[i] = tanhf(c2acc[b * 768 + d] + ldv(c2b, d, bf));
    }
    refine2(y);
    a4[0] = y[0]; a4[1] = y[1]; a4[2] = y[2];
    const float ss = block_sum(s_[0] * s_[0] + s_[1] * s_[1] + s_[2] * s_[2], red);
#pragma unroll
    for (int i = 0; i < 3; ++i) y[i] = sigm(ss * s_[i]);
    refine2(y);
    a5[0] = y[0]; a5[1] = y[1]; a5[2] = y[2];

    float tg[3];
#pragma unroll
    for (int i = 0; i < 3; ++i) tg[i] = ldv(target, t + 256 * i, bf);  // target[0]
    const float u0 = block_sum(a3[0] * tg[0] + a3[1] * tg[1] + a3[2] * tg[2], red);
    const float u1 = block_sum(a4[0] * tg[0] + a4[1] * tg[1] + a4[2] * tg[2], red);
    const float u2 = block_sum(a5[0] * tg[0] + a5[1] * tg[1] + a5[2] * tg[2], red);
    const float mx = fmaxf(u0, fmaxf(u1, u2));
    const float e0 = __expf(u0 - mx), e1 = __expf(u1 - mx), e2 = __expf(u2 - mx);
    const float es = e0 + e1 + e2;
    const float w0 = e0 / es, w1 = e1 / es, w2 = e2 / es;

    float p0 = 0.0f, p1 = 0.0f, p2 = 0.0f;
#pragma unroll
    for (int i = 0; i < 3; ++i) {
        const int d = t + 256 * i;
        const float va = w0 * a3[i], vb = w1 * a4[i], vc = w2 * a5[i];
        p0 += va * ldv(fc2w, d * 3 + 0, bf) + vb * ldv(fc2w, (768 + d) * 3 + 0, bf) + vc * ldv(fc2w, (1536 + d) * 3 + 0, bf);
        p1 += va * ldv(fc2w, d * 3 + 1, bf) + vb * ldv(fc2w, (768 + d) * 3 + 1, bf) + vc * ldv(fc2w, (1536 + d) * 3 + 1, bf);
        p2 += va * ldv(fc2w, d * 3 + 2, bf) + vb * ldv(fc2w, (768 + d) * 3 + 2, bf) + vc * ldv(fc2w, (1536 + d) * 3 + 2, bf);
    }
    p0 = block_sum(p0, red);
    p1 = block_sum(p1, red);
    p2 = block_sum(p2, red);
    if (t == 0) {
        const float o0 = p0 + ldv(fc2b, 0, bf);
        const float o1 = p1 + ldv(fc2b, 1, bf);
        const float o2 = p2 + ldv(fc2b, 2, bf);
        if (bf) {
            ((u16*)outp)[b * 3 + 0] = f2bf(o0);
            ((u16*)outp)[b * 3 + 1] = f2bf(o1);
            ((u16*)outp)[b * 3 + 2] = f2bf(o2);
        } else {
            ((float*)outp)[b * 3 + 0] = o0;
            ((float*)outp)[b * 3 + 1] = o1;
            ((float*)outp)[b * 3 + 2] = o2;
        }
    }
}

extern "C" void kernel_launch(void* const* d_in, const int* in_sizes, int n_in,
                              void* d_out, int out_size, void* d_ws, size_t ws_size,
                              hipStream_t stream) {
    const void* bert   = d_in[0];
    const void* target = d_in[1];
    const void* gc1w   = d_in[2];
    const void* gc1b   = d_in[3];
    const void* gc2w   = d_in[4];
    const void* gc2b   = d_in[5];
    const void* c1w    = d_in[6];
    const void* c1b    = d_in[7];
    const void* c2w    = d_in[8];
    const void* c2b    = d_in[9];
    const void* lng    = d_in[10];
    const void* lnb    = d_in[11];
    const void* fc2w   = d_in[12];
    const void* fc2b   = d_in[13];
    const int*  sb     = (const int*)d_in[14];

    float* sentF = (float*)d_ws;       // 147456 floats
    float* accs  = sentF + 147456;     // 245760 floats
    float* g1acc = accs;               // 64 x 768
    float* c1acc = accs + 49152;       // 64 x 1536  [c1_6 | c1_7]
    float* g2acc = c1acc + 98304;      // 64 x 768
    float* c2acc = g2acc + 49152;      // 64 x 768
    float* flagp = accs + 245760;      // 1 float (dtype flag)

    k1_pool<<<192, 256, 0, stream>>>(bert, sb, sentF, accs, flagp);
    k2_gemm_a<<<216, 256, 0, stream>>>(sentF, gc1w, c1w, g1acc, c1acc, flagp);
    k3_gemm_b<<<108, 256, 0, stream>>>(g1acc, c1acc, gc2w, c2w, gc1b, c1b, g2acc, c2acc, flagp);
    k4_final<<<64, 256, 0, stream>>>(sentF, g2acc, c2acc, gc2b, c2b, lng, lnb,
                                     target, fc2w, fc2b, d_out, flagp);
}

// Round 4
// 223.641 us; speedup vs baseline: 1.1265x; 1.1265x over previous
//
#include <hip/hip_runtime.h>

// Problem: B=64, L=512, D=768, S=8, HOP=3, LAMB=0.5
// Output depends only on sentence segments s in {5,6,7}:
//   g-path needs sent7; conv path c2[:,:,7] needs c1[6],c1[7] -> sent5..7.
// Float dtype (fp32 vs bf16) DETECTED at runtime from bert bit patterns;
// seg_bounds int32 vs int64 detected from sb32[1]==0.  (R3: this passed.)
// Workspace (fp32): sentF 64x2304 | accs g1(64x768) c1(64x1536) g2(64x768)
// c2(64x768) | flag(1)  => ~1.54 MB.
// R4 change: k1 pooling split 4-way per (b,seg) -> 768 blocks + k0 zeroing,
// fp32 atomicAdd accumulation (was 192 latency-bound blocks).

typedef unsigned short u16;
typedef short short8 __attribute__((ext_vector_type(8)));
typedef float f32x4 __attribute__((ext_vector_type(4)));

__device__ __forceinline__ float bf2f(u16 h) {
    unsigned int u = ((unsigned int)h) << 16;
    float f;
    __builtin_memcpy(&f, &u, 4);
    return f;
}
__device__ __forceinline__ u16 f2bf(float f) {
    unsigned int u;
    __builtin_memcpy(&u, &f, 4);
    u = (u + 0x7fffu + ((u >> 16) & 1u)) >> 16;  // RNE
    return (u16)u;
}
__device__ __forceinline__ float sigm(float x) { return 1.0f / (1.0f + __expf(-x)); }

// generic scalar load: bf16 bits or fp32
__device__ __forceinline__ float ldv(const void* p, long i, bool bf) {
    return bf ? bf2f(((const u16*)p)[i]) : ((const float*)p)[i];
}

// dtype detector: even-indexed u16s of fp32 N(0,1) data are mantissa bits
// (uniform -> ~6% in exponent window); of bf16 data they are values (~99%).
__device__ __forceinline__ bool detect_bf16(const u16* bert) {
    int hits = 0;
#pragma unroll
    for (int i = 0; i < 256; i += 2) {
        const int e = (bert[i] >> 7) & 0xFF;
        hits += (e >= 115 && e <= 130) ? 1 : 0;
    }
    return hits > 64;
}

// ---------------------------------------------------------------------------
// k0: zero sentF + accs (393216 floats). grid 384 x 256, float4 per thread.
// ---------------------------------------------------------------------------
__global__ __launch_bounds__(256) void k0_zero(float* __restrict__ ws)
{
    ((float4*)ws)[blockIdx.x * 256 + threadIdx.x] = make_float4(0.f, 0.f, 0.f, 0.f);
}

// ---------------------------------------------------------------------------
// k1: segment mean pool (s = 5,6,7), 4 blocks per (b,si), atomicAdd to sentF
// ---------------------------------------------------------------------------
__global__ __launch_bounds__(256) void k1_pool(
    const void* __restrict__ bertv, const int* __restrict__ sb,
    float* __restrict__ sentF, float* __restrict__ flagp)
{
    const int u = blockIdx.x, t = threadIdx.x;
    const bool bf = detect_bf16((const u16*)bertv);
    const bool is64 = (sb[1] == 0);  // int64 low/high interleave (LE)
    if (u == 0 && t == 0) flagp[0] = bf ? 1.0f : 0.0f;
    const int q = u & 3, v = u >> 2;       // v in [0,192)
    const int b = v / 3, si = v - 3 * (v / 3), s = 5 + si;
    const int i0 = b * 9 + s, i1 = i0 + 1;
    int st = is64 ? sb[2 * i0] : sb[i0];
    int en = is64 ? sb[2 * i1] : sb[i1];
    st = st < 0 ? 0 : (st > 511 ? 511 : st);
    en = en <= st ? st + 1 : (en > 512 ? 512 : en);
    const int n = en - st;
    const int r0 = st + (n * q) / 4;
    const int r1 = st + (n * (q + 1)) / 4;
    float a0 = 0.f, a1 = 0.f, a2 = 0.f;
    if (bf) {
        const u16* base = (const u16*)bertv + (size_t)b * 512 * 768;
        int l = r0;
        for (; l + 1 < r1; l += 2) {
            const u16* p0 = base + (size_t)l * 768;
            const u16* p1 = p0 + 768;
            const u16 x0 = p0[t], x1 = p0[t + 256], x2 = p0[t + 512];
            const u16 y0 = p1[t], y1 = p1[t + 256], y2 = p1[t + 512];
            a0 += bf2f(x0) + bf2f(y0);
            a1 += bf2f(x1) + bf2f(y1);
            a2 += bf2f(x2) + bf2f(y2);
        }
        if (l < r1) {
            const u16* p0 = base + (size_t)l * 768;
            a0 += bf2f(p0[t]);
            a1 += bf2f(p0[t + 256]);
            a2 += bf2f(p0[t + 512]);
        }
    } else {
        const float* base = (const float*)bertv + (size_t)b * 512 * 768;
        int l = r0;
        for (; l + 1 < r1; l += 2) {
            const float* p0 = base + (size_t)l * 768;
            const float* p1 = p0 + 768;
            const float x0 = p0[t], x1 = p0[t + 256], x2 = p0[t + 512];
            const float y0 = p1[t], y1 = p1[t + 256], y2 = p1[t + 512];
            a0 += x0 + y0;
            a1 += x1 + y1;
            a2 += x2 + y2;
        }
        if (l < r1) {
            const float* p0 = base + (size_t)l * 768;
            a0 += p0[t];
            a1 += p0[t + 256];
            a2 += p0[t + 512];
        }
    }
    const float inv = 1.0f / (float)n;
    float* o = sentF + b * 2304 + si * 768;
    atomicAdd(o + t, a0 * inv);
    atomicAdd(o + t + 256, a1 * inv);
    atomicAdd(o + t + 512, a2 * inv);
}

// ---------------------------------------------------------------------------
// GEMM core: out(64 x Nout) += x(64 x K) @ B^T, 64x64 tile, K-chunk [k0,k0+256).
// x is always fp32 (workspace). Weights dtype via `bf`.
// XMODE 0: x raw. XMODE 1: x = tanh(raw + bias[k % 768]).
// WMODE 0: W is [k][n] row-major, n-dim 768 (gc1_w/gc2_w).
// WMODE 1: conv weights (O=768, I=768, 3): B[n][k=kb*768+i] = W[n*2304+i*3+kb].
// mfma_f32_16x16x32_bf16; A[m=lane&15][k=quad*8+j]; B same; C/D col=lane&15,
// row=quad*4+reg.
// ---------------------------------------------------------------------------
template <int XMODE, int WMODE>
__device__ __forceinline__ void gemm_core(
    const float* __restrict__ x, int xstride, const void* __restrict__ bias,
    const void* __restrict__ W, bool bf,
    float* __restrict__ out, int ostride,
    int n0, int k0, u16* As, u16* Bs)
{
    const int t = threadIdx.x;
    const int r = t >> 2;             // 0..63
    const int cseg = (t & 3) * 32;    // 0,32,64,96
    const int wave = t >> 6, lane = t & 63;
    const int lm = lane & 15, lq = lane >> 4;
    f32x4 acc[4] = {};

    for (int kk = 0; kk < 256; kk += 128) {
        const int kg = k0 + kk;
        // ---- stage x -> As (fp32 -> bf16), row stride 136 ----
        {
            const float* xp = x + (size_t)r * xstride + (kg + cseg);
            u16* dst = As + r * 136 + cseg;
#pragma unroll
            for (int i = 0; i < 8; ++i) {
                float4 v = ((const float4*)xp)[i];
                if (XMODE == 1) {
                    int kb = kg + cseg + i * 4;
                    if (kb >= 768) kb -= 768;   // K <= 1536, 4-aligned
                    v.x = tanhf(v.x + ldv(bias, kb, bf));
                    v.y = tanhf(v.y + ldv(bias, kb + 1, bf));
                    v.z = tanhf(v.z + ldv(bias, kb + 2, bf));
                    v.w = tanhf(v.w + ldv(bias, kb + 3, bf));
                }
                ((ushort4*)dst)[i] = make_ushort4(f2bf(v.x), f2bf(v.y), f2bf(v.z), f2bf(v.w));
            }
        }
        // ---- stage W -> Bs as [n][k], row stride 136 ----
        if (WMODE == 0) {
            const int p = t >> 2;             // k-pair: k = 2p, 2p+1
            const int nseg = (t & 3) * 16;    // 16 n's
            u16 q0[16], q1[16];
            if (bf) {
                const u16* w0 = (const u16*)W + (size_t)(kg + 2 * p) * 768 + n0 + nseg;
                ((uint4*)q0)[0] = ((const uint4*)w0)[0];
                ((uint4*)q0)[1] = ((const uint4*)w0)[1];
                ((uint4*)q1)[0] = ((const uint4*)(w0 + 768))[0];
                ((uint4*)q1)[1] = ((const uint4*)(w0 + 768))[1];
            } else {
                const float* w0 = (const float*)W + (size_t)(kg + 2 * p) * 768 + n0 + nseg;
#pragma unroll
                for (int e = 0; e < 4; ++e) {
                    float4 v0 = ((const float4*)w0)[e];
                    float4 v1 = ((const float4*)(w0 + 768))[e];
                    q0[4 * e] = f2bf(v0.x); q0[4 * e + 1] = f2bf(v0.y);
                    q0[4 * e + 2] = f2bf(v0.z); q0[4 * e + 3] = f2bf(v0.w);
                    q1[4 * e] = f2bf(v1.x); q1[4 * e + 1] = f2bf(v1.y);
                    q1[4 * e + 2] = f2bf(v1.z); q1[4 * e + 3] = f2bf(v1.w);
                }
            }
#pragma unroll
            for (int e = 0; e < 16; ++e)
                *(ushort2*)(Bs + (nseg + e) * 136 + 2 * p) = make_ushort2(q0[e], q1[e]);
        } else {
            // conv: within a 128-chunk, kb = kg/768 is constant (768 = 6*128)
            const int kb = kg / 768;
            const int i0c = kg - kb * 768;
            u16 tmp[32];
            if (bf) {
                const u16* wp = (const u16*)W + (size_t)(n0 + r) * 2304 + (size_t)(i0c + cseg) * 3 + kb;
#pragma unroll
                for (int j = 0; j < 32; ++j) tmp[j] = wp[j * 3];
            } else {
                const float* wp = (const float*)W + (size_t)(n0 + r) * 2304 + (size_t)(i0c + cseg) * 3 + kb;
#pragma unroll
                for (int j = 0; j < 32; ++j) tmp[j] = f2bf(wp[j * 3]);
            }
            u16* dst = Bs + r * 136 + cseg;
#pragma unroll
            for (int qq = 0; qq < 8; ++qq)
                ((ushort4*)dst)[qq] = ((ushort4*)tmp)[qq];
        }
        __syncthreads();
        const u16* ap = As + (wave * 16 + lm) * 136 + lq * 8;
        const u16* bp = Bs + lm * 136 + lq * 8;
#pragma unroll
        for (int ks = 0; ks < 4; ++ks) {
            short8 af = *(const short8*)(ap + ks * 32);
#pragma unroll
            for (int nf = 0; nf < 4; ++nf) {
                short8 bfr = *(const short8*)(bp + nf * 16 * 136 + ks * 32);
                acc[nf] = __builtin_amdgcn_mfma_f32_16x16x32_bf16(af, bfr, acc[nf], 0, 0, 0);
            }
        }
        __syncthreads();
    }
#pragma unroll
    for (int nf = 0; nf < 4; ++nf) {
#pragma unroll
        for (int rg = 0; rg < 4; ++rg) {
            const int row = wave * 16 + lq * 4 + rg;
            const int col = n0 + nf * 16 + lm;
            atomicAdd(out + (size_t)row * ostride + col, acc[nf][rg]);
        }
    }
}

// Stage A: g1pre = sent7 @ gc1_w (K=768); c1_6 (K=2304, x=[s5|s6|s7]); c1_7 (K=1536, x=[s6|s7])
__global__ __launch_bounds__(256) void k2_gemm_a(
    const float* __restrict__ sentF, const void* __restrict__ gc1w,
    const void* __restrict__ c1w, float* __restrict__ g1acc, float* __restrict__ c1acc,
    const float* __restrict__ flagp)
{
    __shared__ u16 As[64 * 136];
    __shared__ u16 Bs[64 * 136];
    const bool bf = flagp[0] > 0.5f;
    const int u = blockIdx.x;
    if (u < 36) {
        gemm_core<0, 0>(sentF + 1536, 2304, nullptr, gc1w, bf, g1acc, 768,
                        (u / 3) * 64, (u % 3) * 256, As, Bs);
    } else if (u < 144) {
        const int v = u - 36;
        gemm_core<0, 1>(sentF, 2304, nullptr, c1w, bf, c1acc, 1536,
                        (v / 9) * 64, (v % 9) * 256, As, Bs);
    } else {
        const int v = u - 144;
        gemm_core<0, 1>(sentF + 768, 2304, nullptr, c1w, bf, c1acc + 768, 1536,
                        (v / 6) * 64, (v % 6) * 256, As, Bs);
    }
}

// Stage B: g2pre = tanh(g1+gc1_b) @ gc2_w (K=768); c2pre = tanh(c1+c1b) @ W2 (K=1536)
__global__ __launch_bounds__(256) void k3_gemm_b(
    const float* __restrict__ g1acc, const float* __restrict__ c1acc,
    const void* __restrict__ gc2w, const void* __restrict__ c2w,
    const void* __restrict__ gc1b, const void* __restrict__ c1b,
    float* __restrict__ g2acc, float* __restrict__ c2acc,
    const float* __restrict__ flagp)
{
    __shared__ u16 As[64 * 136];
    __shared__ u16 Bs[64 * 136];
    const bool bf = flagp[0] > 0.5f;
    const int u = blockIdx.x;
    if (u < 36) {
        gemm_core<1, 0>(g1acc, 768, gc1b, gc2w, bf, g2acc, 768,
                        (u / 3) * 64, (u % 3) * 256, As, Bs);
    } else {
        const int v = u - 36;
        gemm_core<1, 1>(c1acc, 1536, c1b, c2w, bf, c2acc, 768,
                        (v / 6) * 64, (v % 6) * 256, As, Bs);
    }
}

// ---------------------------------------------------------------------------
// k4: per-batch refine chains + softmax + fc2
// ---------------------------------------------------------------------------
__device__ __forceinline__ float block_sum(float v, float* red) {
#pragma unroll
    for (int m = 1; m < 64; m <<= 1) v += __shfl_xor(v, m, 64);
    const int wave = threadIdx.x >> 6, lane = threadIdx.x & 63;
    if (lane == 0) red[wave] = v;
    __syncthreads();
    const float r = red[0] + red[1] + red[2] + red[3];
    __syncthreads();
    return r;
}

__global__ __launch_bounds__(256) void k4_final(
    const float* __restrict__ sentF, const float* __restrict__ g2acc,
    const float* __restrict__ c2acc,
    const void* __restrict__ gc2b, const void* __restrict__ c2b,
    const void* __restrict__ lng, const void* __restrict__ lnb,
    const void* __restrict__ target, const void* __restrict__ fc2w,
    const void* __restrict__ fc2b, void* __restrict__ outp,
    const float* __restrict__ flagp)
{
    __shared__ float red[4];
    const bool bf = flagp[0] > 0.5f;
    const int t = threadIdx.x, b = blockIdx.x;
    float s_[3], g_[3], bb_[3];
    const float* srow = sentF + b * 2304 + 1536;  // sent7
#pragma unroll
    for (int i = 0; i < 3; ++i) {
        const int d = t + 256 * i;
        s_[i] = srow[d];
        g_[i] = ldv(lng, d, bf);
        bb_[i] = ldv(lnb, d, bf);
    }

    auto refine2 = [&](float* yv) {
#pragma unroll
        for (int it = 0; it < 2; ++it) {
            const float c = block_sum(yv[0] * s_[0] + yv[1] * s_[1] + yv[2] * s_[2], red);
            float tt[3], sm = 0.0f, sq = 0.0f;
#pragma unroll
            for (int i = 0; i < 3; ++i) {
                tt[i] = sigm(c * s_[i]);
                sm += tt[i];
                sq += tt[i] * tt[i];
            }
            const float m = block_sum(sm, red) * (1.0f / 768.0f);
            const float q = block_sum(sq, red) * (1.0f / 768.0f);
            const float inv = rsqrtf(fmaxf(q - m * m, 0.0f) + 1e-5f);
#pragma unroll
            for (int i = 0; i < 3; ++i)
                yv[i] = 0.5f * ((tt[i] - m) * inv * g_[i] + bb_[i]) + s_[i];
        }
    };

    float a3[3], a4[3], a5[3], y[3];
#pragma unroll
    for (int i = 0; i < 3; ++i) {
        const int d = t + 256 * i;
        y[i] = tanhf(g2acc[b * 768 + d] + ldv(gc2b, d, bf));
    }
    refine2(y);
    a3[0] = y[0]; a3[1] = y[1]; a3[2] = y[2];
#pragma unroll
    for (int i = 0; i < 3; ++i) {
        const int d = t + 256 * i;
        y[i] = tanhf(c2acc[b * 768 + d] + ldv(c2b, d, bf));
    }
    refine2(y);
    a4[0] = y[0]; a4[1] = y[1]; a4[2] = y[2];
    const float ss = block_sum(s_[0] * s_[0] + s_[1] * s_[1] + s_[2] * s_[2], red);
#pragma unroll
    for (int i = 0; i < 3; ++i) y[i] = sigm(ss * s_[i]);
    refine2(y);
    a5[0] = y[0]; a5[1] = y[1]; a5[2] = y[2];

    float tg[3];
#pragma unroll
    for (int i = 0; i < 3; ++i) tg[i] = ldv(target, t + 256 * i, bf);  // target[0]
    const float u0 = block_sum(a3[0] * tg[0] + a3[1] * tg[1] + a3[2] * tg[2], red);
    const float u1 = block_sum(a4[0] * tg[0] + a4[1] * tg[1] + a4[2] * tg[2], red);
    const float u2 = block_sum(a5[0] * tg[0] + a5[1] * tg[1] + a5[2] * tg[2], red);
    const float mx = fmaxf(u0, fmaxf(u1, u2));
    const float e0 = __expf(u0 - mx), e1 = __expf(u1 - mx), e2 = __expf(u2 - mx);
    const float es = e0 + e1 + e2;
    const float w0 = e0 / es, w1 = e1 / es, w2 = e2 / es;

    float p0 = 0.0f, p1 = 0.0f, p2 = 0.0f;
#pragma unroll
    for (int i = 0; i < 3; ++i) {
        const int d = t + 256 * i;
        const float va = w0 * a3[i], vb = w1 * a4[i], vc = w2 * a5[i];
        p0 += va * ldv(fc2w, d * 3 + 0, bf) + vb * ldv(fc2w, (768 + d) * 3 + 0, bf) + vc * ldv(fc2w, (1536 + d) * 3 + 0, bf);
        p1 += va * ldv(fc2w, d * 3 + 1, bf) + vb * ldv(fc2w, (768 + d) * 3 + 1, bf) + vc * ldv(fc2w, (1536 + d) * 3 + 1, bf);
        p2 += va * ldv(fc2w, d * 3 + 2, bf) + vb * ldv(fc2w, (768 + d) * 3 + 2, bf) + vc * ldv(fc2w, (1536 + d) * 3 + 2, bf);
    }
    p0 = block_sum(p0, red);
    p1 = block_sum(p1, red);
    p2 = block_sum(p2, red);
    if (t == 0) {
        const float o0 = p0 + ldv(fc2b, 0, bf);
        const float o1 = p1 + ldv(fc2b, 1, bf);
        const float o2 = p2 + ldv(fc2b, 2, bf);
        if (bf) {
            ((u16*)outp)[b * 3 + 0] = f2bf(o0);
            ((u16*)outp)[b * 3 + 1] = f2bf(o1);
            ((u16*)outp)[b * 3 + 2] = f2bf(o2);
        } else {
            ((float*)outp)[b * 3 + 0] = o0;
            ((float*)outp)[b * 3 + 1] = o1;
            ((float*)outp)[b * 3 + 2] = o2;
        }
    }
}

extern "C" void kernel_launch(void* const* d_in, const int* in_sizes, int n_in,
                              void* d_out, int out_size, void* d_ws, size_t ws_size,
                              hipStream_t stream) {
    const void* bert   = d_in[0];
    const void* target = d_in[1];
    const void* gc1w   = d_in[2];
    const void* gc1b   = d_in[3];
    const void* gc2w   = d_in[4];
    const void* gc2b   = d_in[5];
    const void* c1w    = d_in[6];
    const void* c1b    = d_in[7];
    const void* c2w    = d_in[8];
    const void* c2b    = d_in[9];
    const void* lng    = d_in[10];
    const void* lnb    = d_in[11];
    const void* fc2w   = d_in[12];
    const void* fc2b   = d_in[13];
    const int*  sb     = (const int*)d_in[14];

    float* sentF = (float*)d_ws;       // 147456 floats
    float* accs  = sentF + 147456;     // 245760 floats
    float* g1acc = accs;               // 64 x 768
    float* c1acc = accs + 49152;       // 64 x 1536  [c1_6 | c1_7]
    float* g2acc = c1acc + 98304;      // 64 x 768
    float* c2acc = g2acc + 49152;      // 64 x 768
    float* flagp = accs + 245760;      // 1 float (dtype flag)

    k0_zero<<<384, 256, 0, stream>>>(sentF);   // zeros sentF + accs (393216 f)
    k1_pool<<<768, 256, 0, stream>>>(bert, sb, sentF, flagp);
    k2_gemm_a<<<216, 256, 0, stream>>>(sentF, gc1w, c1w, g1acc, c1acc, flagp);
    k3_gemm_b<<<108, 256, 0, stream>>>(g1acc, c1acc, gc2w, c2w, gc1b, c1b, g2acc, c2acc, flagp);
    k4_final<<<64, 256, 0, stream>>>(sentF, g2acc, c2acc, gc2b, c2b, lng, lnb,
                                     target, fc2w, fc2b, d_out, flagp);
}